// Round 1
// baseline (771.898 us; speedup 1.0000x reference)
//
#include <hip/hip_runtime.h>
#include <cstddef>

#define NQ 4
#define KCODES 1024
#define CD 8
#define DIM 512
#define BATCH 16
#define TLEN 4096
#define TT 32
#define NTHREADS 512

// workspace layout (floats)
#define WS_WIN  0
#define WS_WOUT (NQ * DIM * CD)
#define WS_CBN  (2 * NQ * DIM * CD)
// d_out layout (floats)
#define OUT_ZQ 0
#define OUT_CODES ((size_t)BATCH * DIM * TLEN)
#define OUT_LOSS (OUT_CODES + (size_t)NQ * BATCH * TLEN)

__global__ void rvq_zero(float* out) {
  out[OUT_LOSS] = 0.f;
  out[OUT_LOSS + 1] = 0.f;
}

// Normalize weight-norm weights and codebooks once into workspace.
// ws: w_in transposed [NQ][DIM][CD], w_out [NQ][DIM][CD], cb normalized [NQ][KCODES][CD]
__global__ void rvq_prep(const float* __restrict__ inv, const float* __restrict__ ing,
                         const float* __restrict__ outv, const float* __restrict__ outg,
                         const float* __restrict__ cb, float* __restrict__ ws) {
  const int blk = blockIdx.x, tid = threadIdx.x;
  if (blk < 32) {
    // in_proj rows: 32 rows of length 512, one block each
    const int i = blk >> 3, o = blk & 7;
    const float* v = inv + (size_t)(i * CD + o) * DIM;
    const float a = v[tid], b = v[tid + 256];
    float s = a * a + b * b;
    #pragma unroll
    for (int off = 32; off >= 1; off >>= 1) s += __shfl_xor(s, off);
    __shared__ float red[4];
    if ((tid & 63) == 0) red[tid >> 6] = s;
    __syncthreads();
    const float nrm = fmaxf(sqrtf(red[0] + red[1] + red[2] + red[3]), 1e-12f);
    const float g = ing[i * CD + o];
    ws[WS_WIN + (size_t)((i * DIM + tid) * CD) + o] = (g * a) / nrm;
    ws[WS_WIN + (size_t)((i * DIM + tid + 256) * CD) + o] = (g * b) / nrm;
  } else {
    const int rid = (blk - 32) * 256 + tid;   // 0..6143
    if (rid < NQ * DIM) {
      // out_proj rows: 2048 rows of length 8
      const float* v = outv + (size_t)rid * CD;
      float vv[8]; float n2 = 0.f;
      #pragma unroll
      for (int o = 0; o < 8; ++o) { vv[o] = v[o]; n2 += vv[o] * vv[o]; }
      const float nrm = fmaxf(sqrtf(n2), 1e-12f);
      const float g = outg[rid];
      #pragma unroll
      for (int o = 0; o < 8; ++o) ws[WS_WOUT + (size_t)rid * CD + o] = (g * vv[o]) / nrm;
    } else {
      // codebook rows: 4096 rows of length 8
      const int k = rid - NQ * DIM;
      const float* v = cb + (size_t)k * CD;
      float vv[8]; float n2 = 0.f;
      #pragma unroll
      for (int o = 0; o < 8; ++o) { vv[o] = v[o]; n2 += vv[o] * vv[o]; }
      const float nrm = fmaxf(sqrtf(n2), 1e-12f);
      #pragma unroll
      for (int o = 0; o < 8; ++o) ws[WS_CBN + (size_t)k * CD + o] = vv[o] / nrm;
    }
  }
}

// Fused RVQ: residual tile [512][32] lives in LDS across all 4 codebooks.
// z_q = z - final_residual (read z twice, write z_q once).
__launch_bounds__(NTHREADS, 4)
__global__ void rvq_main(const float* __restrict__ z,
                         const float* __restrict__ b_in, const float* __restrict__ b_out,
                         const float* __restrict__ cb, const float* __restrict__ ws,
                         float* __restrict__ out) {
  extern __shared__ float lds[];
  float* res  = lds;                    // [512][32]        16384 floats
  float* part = lds + DIM * TT;         // [8][32][9]        2304 (pad 9 -> conflict-free)
  float* ze   = part + 8 * TT * 9;      // [32][9]            288
  float* sc   = ze + TT * 9;            // [16][32]           512
  int*   idl  = (int*)(sc + 16 * TT);   // [16][32]           512
  // total 20000 floats = 80000 B -> 2 blocks/CU

  const int tid = threadIdx.x;
  const int bb = blockIdx.x >> 7;           // batch index
  const int t0 = (blockIdx.x & 127) * TT;   // token tile start

  const float* zb = z + (size_t)bb * DIM * TLEN + t0;

  // ---- stage residual tile (coalesced 128B rows)
  {
    const int q = tid & 7, d0 = tid >> 3;
    #pragma unroll
    for (int p = 0; p < 8; ++p) {
      const int d = d0 + p * 64;
      const float4 v = *(const float4*)(zb + (size_t)d * TLEN + q * 4);
      *(float4*)(res + d * TT + q * 4) = v;
    }
  }
  __syncthreads();

  const int t  = tid & 31;   // token within tile
  const int dc = tid >> 5;   // d-chunk 0..15 (32 rows each)
  const int w  = tid >> 6;   // wave 0..7
  float loss_acc = 0.f;

  for (int i = 0; i < NQ; ++i) {
    // ---- in_proj: partial dots over this thread's 32-row d-chunk
    float acc[8] = {0,0,0,0,0,0,0,0};
    {
      const float* wp = ws + WS_WIN + (size_t)(i * DIM + dc * 32) * CD;
      const float* rp = res + dc * 32 * TT + t;
      #pragma unroll 4
      for (int j = 0; j < 32; ++j) {
        const float r = rp[j * TT];
        const float4 w0 = *(const float4*)(wp + j * 8);
        const float4 w1 = *(const float4*)(wp + j * 8 + 4);
        acc[0] += w0.x * r; acc[1] += w0.y * r; acc[2] += w0.z * r; acc[3] += w0.w * r;
        acc[4] += w1.x * r; acc[5] += w1.y * r; acc[6] += w1.z * r; acc[7] += w1.w * r;
      }
    }
    #pragma unroll
    for (int o = 0; o < 8; ++o) acc[o] += __shfl_xor(acc[o], 32);
    if ((tid & 63) < 32) {
      float* pp = part + (w * TT + t) * 9;
      #pragma unroll
      for (int o = 0; o < 8; ++o) pp[o] = acc[o];
    }
    __syncthreads();
    if (tid < 256) {
      const int tt2 = tid >> 3, o = tid & 7;
      float s = b_in[i * CD + o];
      #pragma unroll
      for (int ww = 0; ww < 8; ++ww) s += part[(ww * TT + tt2) * 9 + o];
      ze[tt2 * 9 + o] = s;
    }
    __syncthreads();

    // ---- load e for this thread's token, normalize (faithful eps semantics)
    float e[8], en[8];
    #pragma unroll
    for (int o = 0; o < 8; ++o) e[o] = ze[t * 9 + o];
    float ne2 = 0.f;
    #pragma unroll
    for (int o = 0; o < 8; ++o) ne2 += e[o] * e[o];
    const float ne = sqrtf(ne2);
    const float ned = fmaxf(ne, 1e-12f);
    #pragma unroll
    for (int o = 0; o < 8; ++o) en[o] = e[o] / ned;

    // ---- argmax over this thread's 64-code chunk (codes pre-normalized)
    float best = -1e30f; int bk = 0;
    {
      const float* cp = ws + WS_CBN + (size_t)(i * KCODES + dc * 64) * CD;
      #pragma unroll 4
      for (int k = 0; k < 64; ++k) {
        const float4 c0 = *(const float4*)(cp + k * 8);
        const float4 c1 = *(const float4*)(cp + k * 8 + 4);
        const float s = en[0]*c0.x + en[1]*c0.y + en[2]*c0.z + en[3]*c0.w
                      + en[4]*c1.x + en[5]*c1.y + en[6]*c1.z + en[7]*c1.w;
        if (s > best) { best = s; bk = dc * 64 + k; }
      }
    }
    sc[tid] = best;   // [dc][t] == tid
    idl[tid] = bk;
    __syncthreads();
    // cross-chunk argmax (redundant in every thread; ties -> smallest index)
    best = -1e30f; bk = KCODES;
    #pragma unroll
    for (int cc = 0; cc < 16; ++cc) {
      const float s2 = sc[cc * TT + t];
      const int k2 = idl[cc * TT + t];
      if (s2 > best || (s2 == best && k2 < bk)) { best = s2; bk = k2; }
    }
    if (tid < TT) {
      out[OUT_CODES + (size_t)(i * BATCH + bb) * TLEN + t0 + tid] = (float)bk;
    }

    // ---- fetch raw code vector, loss, rotation trick (per-token, in registers)
    float qv[8];
    {
      const float* qp = cb + (size_t)(i * KCODES + bk) * CD;
      const float4 q0 = *(const float4*)qp;
      const float4 q1 = *(const float4*)(qp + 4);
      qv[0]=q0.x; qv[1]=q0.y; qv[2]=q0.z; qv[3]=q0.w;
      qv[4]=q1.x; qv[5]=q1.y; qv[6]=q1.z; qv[7]=q1.w;
    }
    if (tid < TT) {   // one accumulator per token; commit == codebook numerically
      float s = 0.f;
      #pragma unroll
      for (int o = 0; o < 8; ++o) { const float d2 = e[o] - qv[o]; s += d2 * d2; }
      loss_acc += s;
    }
    float nq2 = 0.f;
    #pragma unroll
    for (int o = 0; o < 8; ++o) nq2 += qv[o] * qv[o];
    const float nq = sqrtf(nq2);
    const float nqd = fmaxf(nq, 1e-12f);
    float qn[8], ru[8];
    float nr2 = 0.f;
    #pragma unroll
    for (int o = 0; o < 8; ++o) { qn[o] = qv[o] / nqd; ru[o] = en[o] + qn[o]; nr2 += ru[o] * ru[o]; }
    const float nrd = fmaxf(sqrtf(nr2), 1e-12f);
    const float scale = nq / fmaxf(ne, 1e-8f);
    float re = 0.f, ene = 0.f;
    #pragma unroll
    for (int o = 0; o < 8; ++o) { ru[o] = ru[o] / nrd; re += ru[o] * e[o]; ene += en[o] * e[o]; }
    float zr[8];
    #pragma unroll
    for (int o = 0; o < 8; ++o) zr[o] = scale * (e[o] - 2.f * ru[o] * re + 2.f * qn[o] * ene);

    // ---- out_proj + in-place residual update on this thread's d-chunk
    {
      const float* wp2 = ws + WS_WOUT + (size_t)(i * DIM + dc * 32) * CD;
      const float* bp2 = b_out + i * DIM + dc * 32;
      float* rp2 = res + dc * 32 * TT + t;
      #pragma unroll 4
      for (int j = 0; j < 32; ++j) {
        const float4 w0 = *(const float4*)(wp2 + j * 8);
        const float4 w1 = *(const float4*)(wp2 + j * 8 + 4);
        float v = bp2[j];
        v += w0.x*zr[0] + w0.y*zr[1] + w0.z*zr[2] + w0.w*zr[3]
           + w1.x*zr[4] + w1.y*zr[5] + w1.z*zr[6] + w1.w*zr[7];
        rp2[j * TT] -= v;
      }
    }
    __syncthreads();
  }

  // ---- output z_q = z - final residual
  {
    const int q = tid & 7, d0 = tid >> 3;
    float* ob = out + OUT_ZQ + (size_t)bb * DIM * TLEN + t0;
    #pragma unroll
    for (int p = 0; p < 8; ++p) {
      const int d = d0 + p * 64;
      const float4 v = *(const float4*)(zb + (size_t)d * TLEN + q * 4);
      const float4 r4 = *(const float4*)(res + d * TT + q * 4);
      float4 ov; ov.x = v.x - r4.x; ov.y = v.y - r4.y; ov.z = v.z - r4.z; ov.w = v.w - r4.w;
      *(float4*)(ob + (size_t)d * TLEN + q * 4) = ov;
    }
  }

  // ---- loss block-reduce (nonzero only in wave-0 lanes 0..31) + atomics
  #pragma unroll
  for (int off = 32; off >= 1; off >>= 1) loss_acc += __shfl_xor(loss_acc, off);
  if (tid == 0) {
    const float lv = loss_acc * (1.f / ((float)CD * TLEN * BATCH));
    atomicAdd(out + OUT_LOSS, lv);       // commitment_loss
    atomicAdd(out + OUT_LOSS + 1, lv);   // codebook_loss (identical forward value)
  }
}

extern "C" void kernel_launch(void* const* d_in, const int* in_sizes, int n_in,
                              void* d_out, int out_size, void* d_ws, size_t ws_size,
                              hipStream_t stream) {
  const float* z    = (const float*)d_in[0];
  const float* inv  = (const float*)d_in[1];
  const float* ing  = (const float*)d_in[2];
  const float* inb  = (const float*)d_in[3];
  const float* outv = (const float*)d_in[4];
  const float* outg = (const float*)d_in[5];
  const float* outb = (const float*)d_in[6];
  const float* cbp  = (const float*)d_in[7];
  float* out = (float*)d_out;
  float* ws  = (float*)d_ws;

  hipLaunchKernelGGL(rvq_zero, dim3(1), dim3(1), 0, stream, out);
  hipLaunchKernelGGL(rvq_prep, dim3(56), dim3(256), 0, stream,
                     inv, ing, outv, outg, cbp, ws);
  hipLaunchKernelGGL(rvq_main, dim3(BATCH * (TLEN / TT)), dim3(NTHREADS),
                     80000, stream, z, inb, outb, cbp, ws, out);
}